// Round 1
// baseline (542.449 us; speedup 1.0000x reference)
//
#include <hip/hip_runtime.h>

// Problem dims (fixed by reference)
#define Bdim 16
#define Sdim 128
#define Mdim 128
#define Ddim 256   // emb dim
#define Hdim 256   // hidden dim
// 2*Ddim = 512 = K of the GEMM

// One block per (b,s) node: streams M*D src + M*D neigh (2 x 128 KiB),
// reduces over M, counts valid neighbor rows, then computes the fused
// row-GEMM + bias + leaky_relu for that node's H outputs.
__global__ __launch_bounds__(256) void gcn_fused_kernel(
    const float* __restrict__ src,
    const float* __restrict__ neigh,
    const float* __restrict__ Wmap,   // [2D, H] row-major
    const float* __restrict__ bmap,   // [H]
    float* __restrict__ out)          // [B*S, H]
{
    const int node = blockIdx.x;          // 0 .. B*S-1
    const int tid  = threadIdx.x;         // 0 .. 255
    const int wave = tid >> 6;            // 0 .. 3
    const int lane = tid & 63;

    const size_t base = (size_t)node * (Mdim * Ddim);
    const float4* __restrict__ src4 = (const float4*)(src + base);
    const float4* __restrict__ ngh4 = (const float4*)(neigh + base);

    // Each row m has D/4 = 64 float4's -> exactly one wave covers a row.
    // Wave w handles rows m = w, w+4, w+8, ...
    float4 sacc = make_float4(0.f, 0.f, 0.f, 0.f);
    float4 nacc = make_float4(0.f, 0.f, 0.f, 0.f);
    int cnt = 0;  // wave-uniform count of valid rows among this wave's rows

    #pragma unroll 4
    for (int m = wave; m < Mdim; m += 4) {
        const int idx = m * (Ddim / 4) + lane;
        float4 sv = src4[idx];
        float4 nv = ngh4[idx];
        sacc.x += sv.x; sacc.y += sv.y; sacc.z += sv.z; sacc.w += sv.w;
        nacc.x += nv.x; nacc.y += nv.y; nacc.z += nv.z; nacc.w += nv.w;
        int nz = (nv.x != 0.f) || (nv.y != 0.f) || (nv.z != 0.f) || (nv.w != 0.f);
        if (__any(nz)) cnt++;   // wave-wide OR over all 256 columns of row m
    }

    __shared__ float s_s[4][Ddim];     // 4 KiB: per-wave partial src sums
    __shared__ float s_n[4][Ddim];     // 4 KiB: per-wave partial neigh sums
    __shared__ int   s_cnt[4];
    __shared__ float hidden[2 * Ddim]; // 2 KiB: the node's GEMM input row

    const int dbase = lane * 4;
    s_s[wave][dbase + 0] = sacc.x;
    s_s[wave][dbase + 1] = sacc.y;
    s_s[wave][dbase + 2] = sacc.z;
    s_s[wave][dbase + 3] = sacc.w;
    s_n[wave][dbase + 0] = nacc.x;
    s_n[wave][dbase + 1] = nacc.y;
    s_n[wave][dbase + 2] = nacc.z;
    s_n[wave][dbase + 3] = nacc.w;
    if (lane == 0) s_cnt[wave] = cnt;
    __syncthreads();

    const float num = (float)(s_cnt[0] + s_cnt[1] + s_cnt[2] + s_cnt[3]);
    const float inv = 1.0f / fmaxf(num, 1.0f);

    // thread t finalizes column t
    const float ssum = s_s[0][tid] + s_s[1][tid] + s_s[2][tid] + s_s[3][tid];
    const float nsum = s_n[0][tid] + s_n[1][tid] + s_n[2][tid] + s_n[3][tid];
    hidden[tid]        = ssum;        // concat: src.sum first
    hidden[Ddim + tid] = nsum * inv;  // then masked neighbor mean
    __syncthreads();

    // Fused GEMM row: out[node][t] = leaky_relu(hidden . W[:,t] + b[t])
    float acc = bmap[tid];
    const float4* __restrict__ h4 = (const float4*)hidden;
    #pragma unroll 4
    for (int k4 = 0; k4 < (2 * Ddim) / 4; ++k4) {
        const float4 h = h4[k4];                   // LDS broadcast
        const int k = k4 * 4;
        acc += h.x * Wmap[(size_t)(k + 0) * Hdim + tid];
        acc += h.y * Wmap[(size_t)(k + 1) * Hdim + tid];
        acc += h.z * Wmap[(size_t)(k + 2) * Hdim + tid];
        acc += h.w * Wmap[(size_t)(k + 3) * Hdim + tid];
    }
    const float r = acc > 0.f ? acc : 0.01f * acc;
    out[(size_t)node * Hdim + tid] = r;
}

extern "C" void kernel_launch(void* const* d_in, const int* in_sizes, int n_in,
                              void* d_out, int out_size, void* d_ws, size_t ws_size,
                              hipStream_t stream) {
    const float* src   = (const float*)d_in[0];
    const float* neigh = (const float*)d_in[1];
    const float* Wmap  = (const float*)d_in[2];
    const float* bmap  = (const float*)d_in[3];
    float* out = (float*)d_out;

    dim3 grid(Bdim * Sdim);   // 2048 blocks, one per node
    dim3 block(256);
    gcn_fused_kernel<<<grid, block, 0, stream>>>(src, neigh, Wmap, bmap, out);
}

// Round 2
// 519.369 us; speedup vs baseline: 1.0444x; 1.0444x over previous
//
#include <hip/hip_runtime.h>

// Problem dims (fixed by reference)
#define Bdim 16
#define Sdim 128
#define Mdim 128
#define Ddim 256   // emb dim
#define Hdim 256   // hidden dim
#define NPB 4      // nodes per block
#define NT  512    // threads per block (8 waves)

// Block = 512 threads = 8 waves, handles 4 nodes (wave pair per node).
// Phase 1: stream M*D src + neigh per node (wave w covers rows m ≡ (w&1) mod 2
//          of node w>>1; 64 lanes * float4 = one full 256-col row per iter,
//          so __any() gives the row-validity bit exactly).
//          4-row batches -> 8 float4 loads in flight per thread.
// Phase 2: LDS combine wave pairs -> hidden[4][512].
// Phase 3: fused GEMM row: W_map read ONCE per block for 4 nodes (4x less L2
//          traffic than 1 node/block), + bias + leaky_relu.
__global__ __launch_bounds__(NT, 4) void gcn_fused2(
    const float* __restrict__ src,
    const float* __restrict__ neigh,
    const float* __restrict__ Wmap,   // [2D, H] row-major
    const float* __restrict__ bmap,   // [H]
    float* __restrict__ out)          // [B*S, H]
{
    const int tid   = threadIdx.x;
    const int wave  = tid >> 6;       // 0..7
    const int lane  = tid & 63;
    const int lnode = wave >> 1;      // 0..3 local node
    const int mph   = wave & 1;       // row phase within node

    const size_t base4 = (size_t)(blockIdx.x * NPB + lnode) * (Mdim * Ddim / 4);
    const float4* __restrict__ src4 = (const float4*)src + base4;
    const float4* __restrict__ ngh4 = (const float4*)neigh + base4;

    float4 sacc = make_float4(0.f, 0.f, 0.f, 0.f);
    float4 nacc = make_float4(0.f, 0.f, 0.f, 0.f);
    int cnt = 0;

    // wave covers 64 rows: m = mph + 2*i, i in [0,64); batch 4 rows
    for (int i0 = 0; i0 < 64; i0 += 4) {
        float4 sv[4], nv[4];
        #pragma unroll
        for (int j = 0; j < 4; ++j) {
            const int m   = mph + 2 * (i0 + j);
            const int idx = m * (Ddim / 4) + lane;
            sv[j] = src4[idx];
            nv[j] = ngh4[idx];
        }
        #pragma unroll
        for (int j = 0; j < 4; ++j) {
            sacc.x += sv[j].x; sacc.y += sv[j].y; sacc.z += sv[j].z; sacc.w += sv[j].w;
            nacc.x += nv[j].x; nacc.y += nv[j].y; nacc.z += nv[j].z; nacc.w += nv[j].w;
            int nz = (nv[j].x != 0.f) | (nv[j].y != 0.f) | (nv[j].z != 0.f) | (nv[j].w != 0.f);
            if (__any(nz)) cnt++;   // wave-wide OR over the row's 256 columns
        }
    }

    __shared__ float s_s[8][Ddim];        // 8 KiB per-wave partial src sums
    __shared__ float s_n[8][Ddim];        // 8 KiB per-wave partial neigh sums
    __shared__ int   s_cnt[8];
    __shared__ float hid[NPB][2 * Ddim];  // 8 KiB GEMM input rows

    *(float4*)&s_s[wave][lane * 4] = sacc;
    *(float4*)&s_n[wave][lane * 4] = nacc;
    if (lane == 0) s_cnt[wave] = cnt;
    __syncthreads();

    // combine wave pairs -> hidden rows. 512 threads cover 4 nodes x 512 cols:
    // threads 0..255 build the src-sum half, 256..511 the neigh-mean half.
    {
        const int t    = tid & (Ddim - 1);
        const int half = tid >> 8;
        #pragma unroll
        for (int n = 0; n < NPB; ++n) {
            if (half == 0) {
                hid[n][t] = s_s[2 * n][t] + s_s[2 * n + 1][t];
            } else {
                const float num = (float)(s_cnt[2 * n] + s_cnt[2 * n + 1]);
                const float inv = 1.0f / fmaxf(num, 1.0f);
                hid[n][Ddim + t] = (s_n[2 * n][t] + s_n[2 * n + 1][t]) * inv;
            }
        }
    }
    __syncthreads();

    // GEMM: thread -> (col t, node pair). Both halves load the same W[k][t]
    // at the same time -> L1 dedup; W read once per block from L2.
    const int t  = tid & (Ddim - 1);
    const int n0 = (tid >> 8) * 2;          // 0 or 2
    float acc0 = bmap[t];
    float acc1 = acc0;
    const float4* __restrict__ h0 = (const float4*)hid[n0];
    const float4* __restrict__ h1 = (const float4*)hid[n0 + 1];

    #pragma unroll 4
    for (int k4 = 0; k4 < (2 * Ddim) / 4; ++k4) {
        const float4 ha = h0[k4];           // ds_read_b128, wave-broadcast
        const float4 hb = h1[k4];
        const int k = k4 * 4;
        const float w0 = Wmap[(size_t)(k + 0) * Hdim + t];
        const float w1 = Wmap[(size_t)(k + 1) * Hdim + t];
        const float w2 = Wmap[(size_t)(k + 2) * Hdim + t];
        const float w3 = Wmap[(size_t)(k + 3) * Hdim + t];
        acc0 = fmaf(ha.x, w0, acc0); acc1 = fmaf(hb.x, w0, acc1);
        acc0 = fmaf(ha.y, w1, acc0); acc1 = fmaf(hb.y, w1, acc1);
        acc0 = fmaf(ha.z, w2, acc0); acc1 = fmaf(hb.z, w2, acc1);
        acc0 = fmaf(ha.w, w3, acc0); acc1 = fmaf(hb.w, w3, acc1);
    }

    const float r0 = acc0 > 0.f ? acc0 : 0.01f * acc0;
    const float r1 = acc1 > 0.f ? acc1 : 0.01f * acc1;
    const size_t row0 = (size_t)blockIdx.x * NPB + n0;
    out[row0 * Hdim + t]       = r0;
    out[(row0 + 1) * Hdim + t] = r1;
}

extern "C" void kernel_launch(void* const* d_in, const int* in_sizes, int n_in,
                              void* d_out, int out_size, void* d_ws, size_t ws_size,
                              hipStream_t stream) {
    const float* src   = (const float*)d_in[0];
    const float* neigh = (const float*)d_in[1];
    const float* Wmap  = (const float*)d_in[2];
    const float* bmap  = (const float*)d_in[3];
    float* out = (float*)d_out;

    dim3 grid((Bdim * Sdim) / NPB);   // 512 blocks, 4 nodes each
    dim3 block(NT);
    gcn_fused2<<<grid, block, 0, stream>>>(src, neigh, Wmap, bmap, out);
}